// Round 2
// baseline (255.670 us; speedup 1.0000x reference)
//
#include <hip/hip_runtime.h>

#define PLANES 384
#define K 11
#define TS 96            // LDS tile row stride in floats; row skew (row&12) breaks bank aliasing
#define ROWS 74          // 5 pad + 64 + 5 pad

// One block = one (n,c) plane of 64x64. 256 threads, each computes a 4x4 output tile.
// LDS layout: tile[row*TS + (row&12) + gx+8] = x[plane][row-5][gx]; borders zeroed (padding).
__global__ __launch_bounds__(256) void smpconv_kernel(
    const float* __restrict__ x,
    const float* __restrict__ wcoord,   // (1,4,2)
    const float* __restrict__ radius,   // (1,4,1,1)
    const float* __restrict__ wts,      // (1,384,4)
    float* __restrict__ out)
{
    __shared__ __align__(16) float tile[ROWS * TS];
    __shared__ __align__(16) float skv[12 * 12];   // 11 kernel rows, stride 12 (b128-aligned)
    __shared__ int s_rcmask[K];                    // per-kernel-row column bitmask

    const int tid = threadIdx.x;
    const int bid = blockIdx.x;          // n*384 + c
    const int c   = bid % PLANES;

    // ---- phase 0: zero LDS tile (zero halo = padding) ----
    #pragma unroll
    for (int z = 0; z < 7; ++z) {
        int e = z * 256 + tid;
        if (e < (ROWS * TS) / 4) {
            float4 zz; zz.x = zz.y = zz.z = zz.w = 0.f;
            *(float4*)&tile[e * 4] = zz;
        }
    }
    if (tid < K) s_rcmask[tid] = 0;
    __syncthreads();

    // ---- phase 1: stage input plane (skewed) + generate this channel's 11x11 kernel ----
    const float* xp = x + (size_t)bid * 4096;
    #pragma unroll
    for (int it = 0; it < 4; ++it) {
        int e = it * 256 + tid;              // float4 index 0..1023
        float4 v = ((const float4*)xp)[e];
        int gy = e >> 4;                     // 16 float4 per 64-wide row
        int gx = (e & 15) << 2;
        int row = gy + 5;
        *(float4*)&tile[row * TS + (row & 12) + gx + 8] = v;
    }
    if (tid < K * K) {
        // kf[c,i,j] = sum_p w[c,p] * relu(1 - (|wc0 - lin[j]| + |wc1 - lin[10-i]|)/r[p])
        int i = tid / K;
        int j = tid - i * K;
        float la = -1.f + 0.2f * (float)j;
        float lb = -1.f + 0.2f * (float)(10 - i);
        float a = 0.f;
        #pragma unroll
        for (int p = 0; p < 4; ++p) {
            float ir = 1.f / radius[p];
            float t = 1.f - (fabsf(wcoord[2*p] - la) + fabsf(wcoord[2*p+1] - lb)) * ir;
            t = fmaxf(t, 0.f);
            a = fmaf(wts[c*4 + p], t, a);
        }
        skv[i * 12 + j] = a;
        if (a != 0.f) atomicOr(&s_rcmask[i], 1 << j);
    }
    __syncthreads();

    // ---- wave-uniform sparsity masks in SGPRs ----
    int rc[K];
    int rowmask = 0, colmask = 0;
    #pragma unroll
    for (int i = 0; i < K; ++i) {
        rc[i] = __builtin_amdgcn_readfirstlane(s_rcmask[i]);
        if (rc[i]) rowmask |= 1 << i;
        colmask |= rc[i];
    }
    // window quad q holds w[4q..4q+3] = taps xx+j+3; needed iff some active j in [4q-6, 4q]
    const bool nq0 = (colmask & 0x001) != 0;
    const bool nq1 = (colmask & 0x01F) != 0;
    const bool nq2 = (colmask & 0x1FC) != 0;
    const bool nq3 = (colmask & 0x7C0) != 0;
    const bool nq4 = (colmask & 0x400) != 0;

    const int ty = tid >> 4;     // 0..15 -> output rows 4ty..4ty+3
    const int tx = tid & 15;     // 0..15 -> output cols 4tx..4tx+3

    float acc[4][4] = {};
    float kvs[4][12] = {};       // rotating cache of 4 kernel rows (fully unrolled -> regs)

    const float* colbase = tile + tx * 4;

    #pragma unroll
    for (int rr = 0; rr < 14; ++rr) {      // input rows 4ty+rr-5
        // rotate in kernel row rr (used by o = 0..3 at iterations rr..rr+3)
        if (rr < K) {
            if ((rowmask >> rr) & 1) {
                const int s = rr & 3;
                const int m = rc[rr];
                if (m & 0x00F) {
                    float4 k = *(const float4*)&skv[rr*12 + 0];
                    kvs[s][0]=k.x; kvs[s][1]=k.y; kvs[s][2]=k.z; kvs[s][3]=k.w;
                }
                if (m & 0x0F0) {
                    float4 k = *(const float4*)&skv[rr*12 + 4];
                    kvs[s][4]=k.x; kvs[s][5]=k.y; kvs[s][6]=k.z; kvs[s][7]=k.w;
                }
                if (m & 0x700) {
                    float4 k = *(const float4*)&skv[rr*12 + 8];
                    kvs[s][8]=k.x; kvs[s][9]=k.y; kvs[s][10]=k.z;
                }
            }
        }
        // need bit (3-o) <=> kernel row i=rr-o exists and is nonzero
        const int need = ((rowmask << 3) >> rr) & 0xF;
        if (need) {
            const int row = ty * 4 + rr;
            const float* rp = colbase + row * TS + (row & 12);   // skewed row base
            float w[20];
            if (nq0) { float4 v = *(const float4*)(rp + 0);  w[0]=v.x;  w[1]=v.y;  w[2]=v.z;  w[3]=v.w; }
            if (nq1) { float4 v = *(const float4*)(rp + 4);  w[4]=v.x;  w[5]=v.y;  w[6]=v.z;  w[7]=v.w; }
            if (nq2) { float4 v = *(const float4*)(rp + 8);  w[8]=v.x;  w[9]=v.y;  w[10]=v.z; w[11]=v.w; }
            if (nq3) { float4 v = *(const float4*)(rp + 12); w[12]=v.x; w[13]=v.y; w[14]=v.z; w[15]=v.w; }
            if (nq4) { float4 v = *(const float4*)(rp + 16); w[16]=v.x; w[17]=v.y; w[18]=v.z; w[19]=v.w; }
            #pragma unroll
            for (int o = 0; o < 4; ++o) {
                if (rr - o >= 0 && rr - o < K) {           // compile-time fold
                    if ((need >> (3 - o)) & 1) {
                        const int m = rc[rr - o];          // per-row column mask (SGPR)
                        const int s = (rr - o) & 3;
                        #pragma unroll
                        for (int j = 0; j < K; ++j) {
                            if ((m >> j) & 1) {
                                const float kv = kvs[s][j];
                                // plane col = 4tx+xx+j-5 -> window index xx+j+3
                                #pragma unroll
                                for (int xx = 0; xx < 4; ++xx)
                                    acc[o][xx] = fmaf(w[xx + j + 3], kv, acc[o][xx]);
                            }
                        }
                    }
                }
            }
        }
    }

    float* op = out + (size_t)bid * 4096 + (ty * 4) * 64 + tx * 4;
    #pragma unroll
    for (int o = 0; o < 4; ++o) {
        float4 v;
        v.x = acc[o][0]; v.y = acc[o][1]; v.z = acc[o][2]; v.w = acc[o][3];
        *(float4*)(op + o * 64) = v;
    }
}

extern "C" void kernel_launch(void* const* d_in, const int* in_sizes, int n_in,
                              void* d_out, int out_size, void* d_ws, size_t ws_size,
                              hipStream_t stream) {
    const float* x      = (const float*)d_in[0];
    const float* wcoord = (const float*)d_in[1];
    const float* radius = (const float*)d_in[2];
    const float* wts    = (const float*)d_in[3];
    float* out          = (float*)d_out;

    const int nplanes = 16 * PLANES;   // 6144 blocks, one 64x64 plane each
    smpconv_kernel<<<dim3(nplanes), dim3(256), 0, stream>>>(x, wcoord, radius, wts, out);
}

// Round 3
// 228.033 us; speedup vs baseline: 1.1212x; 1.1212x over previous
//
#include <hip/hip_runtime.h>

#define PLANES 384
#define K 11
#define TS 92            // row stride in floats; 92 mod 32 = 28, + skew (row&12) -> conflict-free
#define LROWS 42         // 5 halo + 32 + 5 halo

// One block = half a (n,c) plane: 32 output rows x 64 cols. 256 threads,
// each computes a 2x4 output tile. LDS row r holds plane row (base-5+r),
// laid out at tile[r*TS + (r&12) + 8 + col]; halo zeroed (= conv padding).
__global__ __launch_bounds__(256) void smpconv_kernel(
    const float* __restrict__ x,
    const float* __restrict__ wcoord,   // (1,4,2)
    const float* __restrict__ radius,   // (1,4,1,1)
    const float* __restrict__ wts,      // (1,384,4)
    float* __restrict__ out)
{
    __shared__ __align__(16) float tile[LROWS * TS];   // 15456 B
    __shared__ __align__(16) float skv[12 * 12];       // 11 kernel rows, stride 12
    __shared__ int s_rowmask, s_colmask;

    const int tid   = threadIdx.x;
    const int bid   = blockIdx.x;
    const int plane = bid >> 1;          // n*384 + c
    const int base  = (bid & 1) << 5;    // 0 or 32
    const int c     = plane % PLANES;

    // ---- phase 0: zero LDS tile (halo = conv zero padding) ----
    #pragma unroll
    for (int z = 0; z < 4; ++z) {
        int e = z * 256 + tid;
        if (e < (LROWS * TS) / 4) {
            float4 zz; zz.x = zz.y = zz.z = zz.w = 0.f;
            *(float4*)&tile[e * 4] = zz;
        }
    }
    if (tid == 0) { s_rowmask = 0; s_colmask = 0; }
    __syncthreads();

    // ---- phase 1: stage plane rows [base-5, base+36] + generate 11x11 kernel ----
    const float4* xp4 = (const float4*)(x + (size_t)plane * 4096);
    #pragma unroll
    for (int it = 0; it < 3; ++it) {
        int e = it * 256 + tid;              // float4 index within 42x16
        if (e < LROWS * 16) {
            int r   = e >> 4;                // lds row 0..41
            int gx4 = e & 15;                // float4 within row
            int prow = base - 5 + r;
            if (prow >= 0 && prow < 64) {
                float4 v = xp4[prow * 16 + gx4];
                *(float4*)&tile[r * TS + (r & 12) + 8 + (gx4 << 2)] = v;
            }
        }
    }
    if (tid < K * K) {
        // kf[c,i,j] = sum_p w[c,p] * relu(1 - (|wc0 - lin[j]| + |wc1 - lin[10-i]|)/r[p])
        int i = tid / K;
        int j = tid - i * K;
        float la = -1.f + 0.2f * (float)j;
        float lb = -1.f + 0.2f * (float)(10 - i);
        float a = 0.f;
        #pragma unroll
        for (int p = 0; p < 4; ++p) {
            float ir = 1.f / radius[p];
            float t = 1.f - (fabsf(wcoord[2*p] - la) + fabsf(wcoord[2*p+1] - lb)) * ir;
            t = fmaxf(t, 0.f);
            a = fmaf(wts[c*4 + p], t, a);
        }
        skv[i * 12 + j] = a;
        if (a != 0.f) {
            atomicOr(&s_rowmask, 1 << i);
            atomicOr(&s_colmask, 1 << j);
        }
    }
    __syncthreads();

    // wave-uniform rectangle masks (scalar branches; same for every block)
    const int rowmask = __builtin_amdgcn_readfirstlane(s_rowmask);
    const int colmask = __builtin_amdgcn_readfirstlane(s_colmask);

    const int ty = tid >> 4;     // 0..15 -> output rows 2ty, 2ty+1
    const int tx = tid & 15;     // 0..15 -> output cols 4tx..4tx+3

    float acc0[4] = {0.f, 0.f, 0.f, 0.f};
    float acc1[4] = {0.f, 0.f, 0.f, 0.f};
    float kvs[2][12];            // 2-slot rotating kernel-row cache (renamed regs)
    #pragma unroll
    for (int s = 0; s < 2; ++s)
        #pragma unroll
        for (int j = 0; j < 12; ++j) kvs[s][j] = 0.f;

    #pragma unroll
    for (int rr = 0; rr < 12; ++rr) {       // lds row 2ty+rr; kernel row i = rr-o
        const bool n0 = (rr < K)  && ((rowmask >> rr) & 1);
        const bool n1 = (rr >= 1) && ((rowmask >> (rr - 1)) & 1);
        if (n0) {                           // rotate in kernel row rr (unconditional quads)
            const int s = rr & 1;
            float4 k0 = *(const float4*)&skv[rr*12 + 0];
            float4 k1 = *(const float4*)&skv[rr*12 + 4];
            float4 k2 = *(const float4*)&skv[rr*12 + 8];
            kvs[s][0]=k0.x; kvs[s][1]=k0.y; kvs[s][2]=k0.z; kvs[s][3]=k0.w;
            kvs[s][4]=k1.x; kvs[s][5]=k1.y; kvs[s][6]=k1.z; kvs[s][7]=k1.w;
            kvs[s][8]=k2.x; kvs[s][9]=k2.y; kvs[s][10]=k2.z; kvs[s][11]=k2.w;
        }
        if (n0 || n1) {
            const int row = 2 * ty + rr;
            const float* rp = &tile[row * TS + (row & 12) + tx * 4];
            float4 q0 = *(const float4*)(rp + 0);
            float4 q1 = *(const float4*)(rp + 4);
            float4 q2 = *(const float4*)(rp + 8);
            float4 q3 = *(const float4*)(rp + 12);
            float4 q4 = *(const float4*)(rp + 16);
            float w[20];
            w[0]=q0.x;  w[1]=q0.y;  w[2]=q0.z;  w[3]=q0.w;
            w[4]=q1.x;  w[5]=q1.y;  w[6]=q1.z;  w[7]=q1.w;
            w[8]=q2.x;  w[9]=q2.y;  w[10]=q2.z; w[11]=q2.w;
            w[12]=q3.x; w[13]=q3.y; w[14]=q3.z; w[15]=q3.w;
            w[16]=q4.x; w[17]=q4.y; w[18]=q4.z; w[19]=q4.w;
            if (n0) {
                const int s = rr & 1;
                #pragma unroll
                for (int j = 0; j < K; ++j) {
                    if ((colmask >> j) & 1) {
                        const float kv = kvs[s][j];
                        #pragma unroll
                        for (int xx = 0; xx < 4; ++xx)
                            acc0[xx] = fmaf(w[xx + j + 3], kv, acc0[xx]);
                    }
                }
            }
            if (n1) {
                const int s = (rr - 1) & 1;
                #pragma unroll
                for (int j = 0; j < K; ++j) {
                    if ((colmask >> j) & 1) {
                        const float kv = kvs[s][j];
                        #pragma unroll
                        for (int xx = 0; xx < 4; ++xx)
                            acc1[xx] = fmaf(w[xx + j + 3], kv, acc1[xx]);
                    }
                }
            }
        }
    }

    float* op = out + (size_t)plane * 4096 + (base + 2 * ty) * 64 + tx * 4;
    float4 v0; v0.x = acc0[0]; v0.y = acc0[1]; v0.z = acc0[2]; v0.w = acc0[3];
    float4 v1; v1.x = acc1[0]; v1.y = acc1[1]; v1.z = acc1[2]; v1.w = acc1[3];
    *(float4*)(op)      = v0;
    *(float4*)(op + 64) = v1;
}

extern "C" void kernel_launch(void* const* d_in, const int* in_sizes, int n_in,
                              void* d_out, int out_size, void* d_ws, size_t ws_size,
                              hipStream_t stream) {
    const float* x      = (const float*)d_in[0];
    const float* wcoord = (const float*)d_in[1];
    const float* radius = (const float*)d_in[2];
    const float* wts    = (const float*)d_in[3];
    float* out          = (float*)d_out;

    const int nblocks = 16 * PLANES * 2;   // 12288 half-plane blocks
    smpconv_kernel<<<dim3(nblocks), dim3(256), 0, stream>>>(x, wcoord, radius, wts, out);
}

// Round 4
// 209.102 us; speedup vs baseline: 1.2227x; 1.0905x over previous
//
#include <hip/hip_runtime.h>

#define PLANES 384
#define K 11
#define TS 88            // row stride in floats; rows in a wave differ by 4 -> skew (row&12) gives distinct bank-quads
#define ROWS 74          // 5 pad + 64 + 5 pad

// One block = one (n,c) plane of 64x64. 256 threads, each computes a 4x4 output tile.
// LDS layout: tile[row*TS + (row&12) + 8 + gx] = x[plane][row-5][gx]; halo zeroed (padding).
// Window reads may spill <=4 floats past a row's stride into the next row's always-zero
// left-pad region (data starts at index skew+8 >= 8); +16 array pad covers the last row.
__global__ __launch_bounds__(256) void smpconv_kernel(
    const float* __restrict__ x,
    const float* __restrict__ wcoord,   // (1,4,2)
    const float* __restrict__ radius,   // (1,4,1,1)
    const float* __restrict__ wts,      // (1,384,4)
    float* __restrict__ out)
{
    __shared__ __align__(16) float tile[ROWS * TS + 16];   // 26176 B
    __shared__ __align__(16) float skv[12 * 12];           // 11 kernel rows, stride 12
    __shared__ int s_rcmask[K];                            // per-kernel-row column bitmask

    const int tid = threadIdx.x;
    const int bid = blockIdx.x;          // n*384 + c
    const int c   = bid % PLANES;

    // ---- phase 0: zero LDS tile (halo = conv zero padding) ----
    #pragma unroll
    for (int z = 0; z < 7; ++z) {
        int e = z * 256 + tid;
        if (e < (ROWS * TS + 16) / 4) {
            float4 zz; zz.x = zz.y = zz.z = zz.w = 0.f;
            *(float4*)&tile[e * 4] = zz;
        }
    }
    if (tid < K) s_rcmask[tid] = 0;
    __syncthreads();

    // ---- phase 1: stage input plane (skewed) + generate this channel's 11x11 kernel ----
    const float* xp = x + (size_t)bid * 4096;
    #pragma unroll
    for (int it = 0; it < 4; ++it) {
        int e = it * 256 + tid;              // float4 index 0..1023
        float4 v = ((const float4*)xp)[e];
        int gy = e >> 4;                     // 16 float4 per 64-wide row
        int gx = (e & 15) << 2;
        int row = gy + 5;
        *(float4*)&tile[row * TS + (row & 12) + 8 + gx] = v;
    }
    if (tid < K * K) {
        // kf[c,i,j] = sum_p w[c,p] * relu(1 - (|wc0 - lin[j]| + |wc1 - lin[10-i]|)/r[p])
        int i = tid / K;
        int j = tid - i * K;
        float la = -1.f + 0.2f * (float)j;
        float lb = -1.f + 0.2f * (float)(10 - i);
        float a = 0.f;
        #pragma unroll
        for (int p = 0; p < 4; ++p) {
            float ir = 1.f / radius[p];
            float t = 1.f - (fabsf(wcoord[2*p] - la) + fabsf(wcoord[2*p+1] - lb)) * ir;
            t = fmaxf(t, 0.f);
            a = fmaf(wts[c*4 + p], t, a);
        }
        skv[i * 12 + j] = a;
        if (a != 0.f) atomicOr(&s_rcmask[i], 1 << j);
    }
    __syncthreads();

    // ---- wave-uniform sparsity masks in SGPRs (scalar branches only; no conditional loads) ----
    int rc[K];
    int rowmask = 0;
    #pragma unroll
    for (int i = 0; i < K; ++i) {
        rc[i] = __builtin_amdgcn_readfirstlane(s_rcmask[i]);
        if (rc[i]) rowmask |= 1 << i;
    }

    const int ty = tid >> 4;     // 0..15 -> output rows 4ty..4ty+3
    const int tx = tid & 15;     // 0..15 -> output cols 4tx..4tx+3

    float acc[4][4] = {};
    float kvs[4][12] = {};       // rotating cache of 4 kernel rows (fully unrolled -> regs)

    const float* colbase = tile + tx * 4;

    #pragma unroll
    for (int rr = 0; rr < 14; ++rr) {      // input rows 4ty+rr-5; kernel row i = rr-o
        // rotate in kernel row rr (UNCONDITIONAL quads when row active -> no cond-defined regs)
        if (rr < K) {
            if ((rowmask >> rr) & 1) {
                const int s = rr & 3;
                float4 k0 = *(const float4*)&skv[rr*12 + 0];
                float4 k1 = *(const float4*)&skv[rr*12 + 4];
                float4 k2 = *(const float4*)&skv[rr*12 + 8];
                kvs[s][0]=k0.x; kvs[s][1]=k0.y; kvs[s][2]=k0.z; kvs[s][3]=k0.w;
                kvs[s][4]=k1.x; kvs[s][5]=k1.y; kvs[s][6]=k1.z; kvs[s][7]=k1.w;
                kvs[s][8]=k2.x; kvs[s][9]=k2.y; kvs[s][10]=k2.z; kvs[s][11]=k2.w;
            }
        }
        // need bit (3-o) <=> kernel row i=rr-o exists and is nonzero
        const int need = ((rowmask << 3) >> rr) & 0xF;
        if (need) {
            const int row = ty * 4 + rr;
            const float* rp = colbase + row * TS + (row & 12);   // skewed row base
            float4 q0 = *(const float4*)(rp + 0);
            float4 q1 = *(const float4*)(rp + 4);
            float4 q2 = *(const float4*)(rp + 8);
            float4 q3 = *(const float4*)(rp + 12);
            float4 q4 = *(const float4*)(rp + 16);
            float w[20];
            w[0]=q0.x;  w[1]=q0.y;  w[2]=q0.z;  w[3]=q0.w;
            w[4]=q1.x;  w[5]=q1.y;  w[6]=q1.z;  w[7]=q1.w;
            w[8]=q2.x;  w[9]=q2.y;  w[10]=q2.z; w[11]=q2.w;
            w[12]=q3.x; w[13]=q3.y; w[14]=q3.z; w[15]=q3.w;
            w[16]=q4.x; w[17]=q4.y; w[18]=q4.z; w[19]=q4.w;
            #pragma unroll
            for (int o = 0; o < 4; ++o) {
                if (rr - o >= 0 && rr - o < K) {           // compile-time fold
                    if ((need >> (3 - o)) & 1) {
                        const int m = rc[rr - o];          // per-row column mask (SGPR)
                        const int s = (rr - o) & 3;
                        #pragma unroll
                        for (int j = 0; j < K; ++j) {
                            if ((m >> j) & 1) {            // scalar branch gates FMAs only
                                const float kv = kvs[s][j];
                                // plane col = 4tx+xx+j-5 -> window index xx+j+3
                                #pragma unroll
                                for (int xx = 0; xx < 4; ++xx)
                                    acc[o][xx] = fmaf(w[xx + j + 3], kv, acc[o][xx]);
                            }
                        }
                    }
                }
            }
        }
    }

    float* op = out + (size_t)bid * 4096 + (ty * 4) * 64 + tx * 4;
    #pragma unroll
    for (int o = 0; o < 4; ++o) {
        float4 v;
        v.x = acc[o][0]; v.y = acc[o][1]; v.z = acc[o][2]; v.w = acc[o][3];
        *(float4*)(op + o * 64) = v;
    }
}

extern "C" void kernel_launch(void* const* d_in, const int* in_sizes, int n_in,
                              void* d_out, int out_size, void* d_ws, size_t ws_size,
                              hipStream_t stream) {
    const float* x      = (const float*)d_in[0];
    const float* wcoord = (const float*)d_in[1];
    const float* radius = (const float*)d_in[2];
    const float* wts    = (const float*)d_in[3];
    float* out          = (float*)d_out;

    const int nplanes = 16 * PLANES;   // 6144 blocks, one 64x64 plane each
    smpconv_kernel<<<dim3(nplanes), dim3(256), 0, stream>>>(x, wcoord, radius, wts, out);
}